// Round 3
// baseline (299.316 us; speedup 1.0000x reference)
//
#include <hip/hip_runtime.h>

// HelixMemory, fp32 I/O.
// out rows 510..2557 = raw copy: memory[512:2558] ++ inputs[0:2]  (out row r <- new_memory row r+2)
// out rows 0..509    = binary avg-pool hierarchy over memory rows 1024..1535 only (tree map below).
//
// v3 (= v2 theory, hedged copy structure):
//  1. Copy path: persistent sweep, 2048 blocks, each block owns a CONTIGUOUS 3072-chunk span
//     (6 compact rows); 12 f32x4 chunks/thread in 3 batches of 4 independent nt loads ->
//     4 nt stores. Replaces baseline's 16384 one-row blocks (2 loads/wave, full HBM latency
//     exposed, heavy block churn). Contiguous per-block span = better DRAM page locality.
//  2. Pool blocks write the raw-copy output for rows they already load (memory rows
//     1024..1535 -> out rows 1022..1533), eliminating the 33.5 MB redundant HBM re-read
//     (copy loads are nt, so they never populated L2 for the pool pass).
// Copy decode: compact chunk g in [0,6291456) covers rows j in [0,512)u[1024,2048) x 8 batches.
//   vr=g>>9 (compact row), c=g&511, t=vr>>9 in [0,24), b=(t*21846)>>16 = t/3 exact,
//   rs=vr-b*1536, j=rs+(rs>=512?512:0), dst chunk d=(b*2558+510+j)*512+c,
//   memory src = d+1024 chunks (out row r <- memory row r+2), inputs src for j>=2046.
// Bounds (audited): max d=10,477,567 < 10,477,568; max mem src=10,477,567; max in src
//   3,671,039 < 4,194,304. Branch wave-uniform (64-aligned wave span never crosses row).

typedef __attribute__((ext_vector_type(4))) float f32x4;

#define B_    8
#define D_    2048
#define MEMR_ 2558
#define OUTR_ 2558
#define INR_  1024

#define POOL_DT     64                     // 64 col-tiles of 32 floats
#define POOL_BLOCKS (B_ * POOL_DT)         // 512
#define COPY_BLOCKS 2048
#define CHUNKS_PER_BLOCK 3072              // 6 compact rows x 512 chunks

__device__ __forceinline__ void write_row(float* dst, const float* s, float scale) {
  f32x4 o;
#pragma unroll
  for (int e = 0; e < 4; ++e) o[e] = s[e] * scale;
  __builtin_nontemporal_store(o, reinterpret_cast<f32x4*>(dst));
}

__global__ __launch_bounds__(256) void helix_kernel(
    const float* __restrict__ inputs,
    const float* __restrict__ memory,
    float* __restrict__ out) {
  __shared__ float lds[32 * 32];
  const int bid = blockIdx.x;
  const int tid = threadIdx.x;

  if (bid < POOL_BLOCKS) {
    // ---- pool-tree blocks: one (batch, 32-column tile) each ----
    const int b  = bid >> 6;           // / POOL_DT
    const int dt = bid & 63;
    const int q  = tid >> 3;           // 0..31 : row-group (16 fallout rows each)
    const int c  = tid & 7;            // 0..7  : float4 column within tile
    const int dcol = dt * 32 + c * 4;

    // tree source: fallout rows 512..1023 == memory rows 1024..1535
    const float* fall = memory + ((long)b * MEMR_ + 1024) * D_ + dcol;
    float* ob  = out + (long)b * OUTR_ * D_ + dcol;
    float* ob2 = out + ((long)b * OUTR_ + 1022) * D_ + dcol;   // raw-copy dst for these rows

    float f[4], s1[4], s2[4], s3[4], s4[4];
    const float* rp = fall + (long)(q * 16) * D_;

#pragma unroll
    for (int j = 0; j < 16; ++j) {
      f32x4 u = *reinterpret_cast<const f32x4*>(rp + (long)j * D_);
      // absorb the raw copy of this row (out row 1022 + q*16 + j)
      __builtin_nontemporal_store(u, reinterpret_cast<f32x4*>(ob2 + (long)(q * 16 + j) * D_));
#pragma unroll
      for (int e = 0; e < 4; ++e) f[e] = u[e];
      if ((j & 1) == 0) {
#pragma unroll
        for (int e = 0; e < 4; ++e) s1[e] = f[e];
      } else {
#pragma unroll
        for (int e = 0; e < 4; ++e) s1[e] += f[e];
        const int i1 = 256 + 8 * q + (j >> 1);            // P1 index in [256,512)
        if (i1 >= 384) write_row(ob + (long)(i1 - 130) * D_, s1, 0.5f);
        if ((j & 3) == 1) {
#pragma unroll
          for (int e = 0; e < 4; ++e) s2[e] = s1[e];
        } else {
#pragma unroll
          for (int e = 0; e < 4; ++e) s2[e] += s1[e];
          const int i2 = 128 + 4 * q + (j >> 2);          // P2 in [128,256)
          write_row(ob + (long)(254 + i2) * D_, s2, 0.25f);
          if (i2 >= 192) write_row(ob + (long)(i2 - 66) * D_, s2, 0.25f);
          if ((j & 7) == 3) {
#pragma unroll
            for (int e = 0; e < 4; ++e) s3[e] = s2[e];
          } else {
#pragma unroll
            for (int e = 0; e < 4; ++e) s3[e] += s2[e];
            const int i3 = 64 + 2 * q + (j >> 3);         // P3 in [64,128)
            write_row(ob + (long)(126 + i3) * D_, s3, 0.125f);
            if (i3 >= 96) write_row(ob + (long)(i3 - 34) * D_, s3, 0.125f);
            if (j == 7) {
#pragma unroll
              for (int e = 0; e < 4; ++e) s4[e] = s3[e];
            } else if (j == 15) {
#pragma unroll
              for (int e = 0; e < 4; ++e) s4[e] += s3[e];
              const int i4 = 32 + q;                      // P4 in [32,64)
              write_row(ob + (long)(62 + i4) * D_, s4, 0.0625f);
              if (i4 >= 48) write_row(ob + (long)(i4 - 18) * D_, s4, 0.0625f);
            }
          }
        }
      }
    }

    // stash 16-row sums, then LDS tree for levels 5..9
    float* myl = lds + q * 32 + c * 4;
#pragma unroll
    for (int e = 0; e < 4; ++e) myl[e] = s4[e];

    int nq = 16;
    float scale = 1.0f / 32.0f;
    for (int l = 5; l <= 9; ++l) {
      __syncthreads();
      float a[4], bb[4];
      const bool act = (q < nq);
      if (act) {
#pragma unroll
        for (int e = 0; e < 4; ++e) {
          a[e]  = lds[(2 * q) * 32 + c * 4 + e];
          bb[e] = lds[(2 * q + 1) * 32 + c * 4 + e];
        }
      }
      __syncthreads();
      if (act) {
#pragma unroll
        for (int e = 0; e < 4; ++e) a[e] += bb[e];
#pragma unroll
        for (int e = 0; e < 4; ++e) lds[q * 32 + c * 4 + e] = a[e];
        const int i = nq + q;                              // P_l index in [2^(9-l), 2^(10-l))
        write_row(ob + (long)((1 << (10 - l)) - 2 + i) * D_, a, scale);
        if (l < 9 && i >= (3 << (8 - l)))
          write_row(ob + (long)((1 << (9 - l)) - 2 + i - (3 << (8 - l))) * D_, a, scale);
      }
      nq >>= 1;
      scale *= 0.5f;
    }
  } else {
    // ---- copy blocks: contiguous 3072-chunk span each; rows j in [0,512) u [1024,2048) ----
    const int bid2 = bid - POOL_BLOCKS;
    const unsigned base = (unsigned)bid2 * (unsigned)CHUNKS_PER_BLOCK;
    const f32x4* mem4 = reinterpret_cast<const f32x4*>(memory);
    const f32x4* in4  = reinterpret_cast<const f32x4*>(inputs);
    f32x4* out4 = reinterpret_cast<f32x4*>(out);

#pragma unroll 1
    for (int it = 0; it < 3; ++it) {
      f32x4 val[4];
      unsigned dd[4];
#pragma unroll
      for (int k = 0; k < 4; ++k) {
        const unsigned g  = base + (unsigned)(it * 4 + k) * 256u + (unsigned)tid;
        const unsigned vr = g >> 9;                        // compact row [0,12288)
        const unsigned c  = g & 511u;                      // f32x4 col within row
        const unsigned t  = vr >> 9;                       // [0,24)
        const unsigned b  = (t * 21846u) >> 16;            // t/3 exact
        const unsigned rs = vr - b * 1536u;                // [0,1536)
        const unsigned j  = rs + ((rs >= 512u) ? 512u : 0u);  // skip pool-owned rows
        const unsigned d  = (b * (unsigned)MEMR_ + 510u + j) * 512u + c;  // dst chunk
        dd[k] = d;
        const f32x4* sp = (j < 2046u)
            ? (mem4 + (d + 1024u))
            : (in4 + (((b << 10) + (j - 2046u)) * 512u + c));
        val[k] = __builtin_nontemporal_load(sp);
      }
#pragma unroll
      for (int k = 0; k < 4; ++k)
        __builtin_nontemporal_store(val[k], out4 + dd[k]);
    }
  }
}

extern "C" void kernel_launch(void* const* d_in, const int* in_sizes, int n_in,
                              void* d_out, int out_size, void* d_ws, size_t ws_size,
                              hipStream_t stream) {
  const float* inputs = (const float*)d_in[0];
  const float* memory = (const float*)d_in[1];
  float* out = (float*)d_out;
  helix_kernel<<<dim3(POOL_BLOCKS + COPY_BLOCKS), dim3(256), 0, stream>>>(inputs, memory, out);
}